// Round 7
// baseline (86.883 us; speedup 1.0000x reference)
//
#include <hip/hip_runtime.h>

typedef float float4v __attribute__((ext_vector_type(4)));

#define DIM 128

__device__ __forceinline__ float4v ntload(const float* p) {
    return __builtin_nontemporal_load((const float4v*)p);
}

__device__ __forceinline__ void accmax(float4v& acc, const float4v& v) {
    acc.x = fmaxf(acc.x, v.x);
    acc.y = fmaxf(acc.y, v.y);
    acc.z = fmaxf(acc.z, v.z);
    acc.w = fmaxf(acc.w, v.w);
}

// One block (2 waves, 128 threads) per segment. batch is sorted; segment g
// occupies rows [lower_bound(g), lower_bound(g+1)). Bounds via cooperative
// 32-ary ballot search. Streaming max with an 8-deep explicit load pipeline
// (8-16 dwordx4 in flight per wave), non-temporal loads.
__global__ __launch_bounds__(128, 4) void segmax_kernel(
    const float* __restrict__ x, const int* __restrict__ batch,
    float* __restrict__ out, int N)
{
    __shared__ float red[2][DIM];

    int seg  = blockIdx.x;
    int tid  = threadIdx.x;
    int w    = tid >> 6;        // wave id 0/1
    int lane = tid & 63;
    int sub  = lane & 31;       // position within 32-lane search group
    int which = lane >> 5;      // 0: query seg, 1: query seg+1 (also half-wave id)
    int c    = sub * 4;         // column offset (float4 per lane)

    // ---- cooperative 32-ary lower_bound over sorted batch ----
    int g = seg + which;
    unsigned long long gmask = which ? 0xFFFFFFFF00000000ULL : 0x00000000FFFFFFFFULL;
    int lo = 0, len = N;
    #pragma unroll
    for (int it = 0; it < 4; ++it) {
        int L = len;
        int p = lo + ((sub * L) >> 5);          // 32 evenly spaced probes
        int pos = min(p, N - 1);
        bool pred = (L > 0) && (batch[pos] < g);
        unsigned long long bal = __ballot(pred);
        int cnt = __popcll(bal & gmask);        // index of first probe >= g
        if (L > 32) {                           // uniform within each 32-group
            int nlo = (cnt == 0)  ? lo       : (lo + (((cnt - 1) * L) >> 5) + 1);
            int pc  = (cnt == 32) ? (lo + L) : (lo + ((cnt * L) >> 5));
            lo = nlo;
            len = pc - nlo;                     // <= ceil(L/32)
        }
    }
    {   // final: len <= 32, one parallel probe resolves exactly
        int pos = min(lo + ((sub < len) ? sub : 0), N - 1);
        bool pred = (sub < len) && (batch[pos] < g);
        unsigned long long bal = __ballot(pred);
        lo += __popcll(bal & gmask);
    }
    int r0 = __shfl(lo, 0);     // lower_bound(seg)
    int r1 = __shfl(lo, 32);    // lower_bound(seg+1)

    // ---- streaming max over [r0, r1), 8-deep load pipeline ----
    float4v acc;
    acc.x = -INFINITY; acc.y = -INFINITY; acc.z = -INFINITY; acc.w = -INFINITY;

    const float* xc = x + c;
    int half = which;
    // Block covers 4 consecutive rows per step: row = r0 + 2*w + half + 4k.
    int r = r0 + 2 * w + half;

#define LOAD8(p0,p1,p2,p3,p4,p5,p6,p7, base)                      \
    p0 = ntload(xc + (size_t)(base) * DIM);                        \
    p1 = ntload(xc + (size_t)((base) + 4) * DIM);                  \
    p2 = ntload(xc + (size_t)((base) + 8) * DIM);                  \
    p3 = ntload(xc + (size_t)((base) + 12) * DIM);                 \
    p4 = ntload(xc + (size_t)((base) + 16) * DIM);                 \
    p5 = ntload(xc + (size_t)((base) + 20) * DIM);                 \
    p6 = ntload(xc + (size_t)((base) + 24) * DIM);                 \
    p7 = ntload(xc + (size_t)((base) + 28) * DIM)

#define CONSUME8(p0,p1,p2,p3,p4,p5,p6,p7)                          \
    acc.x = fmaxf(fmaxf(fmaxf(acc.x, p0.x), fmaxf(p1.x, p2.x)),    \
                  fmaxf(fmaxf(p3.x, p4.x), fmaxf(p5.x, fmaxf(p6.x, p7.x)))); \
    acc.y = fmaxf(fmaxf(fmaxf(acc.y, p0.y), fmaxf(p1.y, p2.y)),    \
                  fmaxf(fmaxf(p3.y, p4.y), fmaxf(p5.y, fmaxf(p6.y, p7.y)))); \
    acc.z = fmaxf(fmaxf(fmaxf(acc.z, p0.z), fmaxf(p1.z, p2.z)),    \
                  fmaxf(fmaxf(p3.z, p4.z), fmaxf(p5.z, fmaxf(p6.z, p7.z)))); \
    acc.w = fmaxf(fmaxf(fmaxf(acc.w, p0.w), fmaxf(p1.w, p2.w)),    \
                  fmaxf(fmaxf(p3.w, p4.w), fmaxf(p5.w, fmaxf(p6.w, p7.w))))

    if (r + 28 < r1) {
        float4v a0, a1, a2, a3, a4, a5, a6, a7;
        LOAD8(a0, a1, a2, a3, a4, a5, a6, a7, r);
        r += 32;
        for (; r + 28 < r1; r += 32) {
            float4v b0, b1, b2, b3, b4, b5, b6, b7;
            LOAD8(b0, b1, b2, b3, b4, b5, b6, b7, r);
            CONSUME8(a0, a1, a2, a3, a4, a5, a6, a7);
            a0 = b0; a1 = b1; a2 = b2; a3 = b3;
            a4 = b4; a5 = b5; a6 = b6; a7 = b7;
        }
        CONSUME8(a0, a1, a2, a3, a4, a5, a6, a7);
    }
#undef LOAD8
#undef CONSUME8

    // Tail rows.
    for (; r < r1; r += 4) {
        float4v v = ntload(xc + (size_t)r * DIM);
        accmax(acc, v);
    }

    // Combine the two half-wave partials within the wave.
    acc.x = fmaxf(acc.x, __shfl_xor(acc.x, 32));
    acc.y = fmaxf(acc.y, __shfl_xor(acc.y, 32));
    acc.z = fmaxf(acc.z, __shfl_xor(acc.z, 32));
    acc.w = fmaxf(acc.w, __shfl_xor(acc.w, 32));

    // Cross-wave combine via LDS, then direct store.
    if (half == 0) {
        *(float4v*)&red[w][c] = acc;
    }
    __syncthreads();
    if (tid < 32) {
        int cc = tid * 4;
        float4v a = *(const float4v*)&red[0][cc];
        float4v b = *(const float4v*)&red[1][cc];
        a.x = fmaxf(a.x, b.x);
        a.y = fmaxf(a.y, b.y);
        a.z = fmaxf(a.z, b.z);
        a.w = fmaxf(a.w, b.w);
        *(float4v*)(out + (size_t)seg * DIM + cc) = a;
    }
}

extern "C" void kernel_launch(void* const* d_in, const int* in_sizes, int n_in,
                              void* d_out, int out_size, void* d_ws, size_t ws_size,
                              hipStream_t stream) {
    const float* x = (const float*)d_in[0];
    const int* batch = (const int*)d_in[1];
    float* out = (float*)d_out;

    int N = in_sizes[1];              // number of rows
    int G = out_size / DIM;           // number of segments

    segmax_kernel<<<G, 128, 0, stream>>>(x, batch, out, N);
}